// Round 1
// baseline (391.645 us; speedup 1.0000x reference)
//
#include <hip/hip_runtime.h>

typedef unsigned short u16;
typedef unsigned int u32;
typedef short v8s __attribute__((ext_vector_type(8)));
typedef float v4f __attribute__((ext_vector_type(4)));
typedef float v16f __attribute__((ext_vector_type(16)));

#define MFMA16(a, b, c) __builtin_amdgcn_mfma_f32_16x16x32_bf16((a), (b), (c), 0, 0, 0)
#define MFMA32(a, b, c) __builtin_amdgcn_mfma_f32_32x32x16_bf16((a), (b), (c), 0, 0, 0)

static __device__ __forceinline__ u16 f2bf(float f) {
    u32 u = __float_as_uint(f);
    u += 0x7fffu + ((u >> 16) & 1u);   // RNE
    return (u16)(u >> 16);
}

// async global->LDS, 16B per lane. LDS dest must be wave-uniform base + lane*16.
static __device__ __forceinline__ void gl2lds(const u16* g, u16* l) {
    __builtin_amdgcn_global_load_lds(
        (const __attribute__((address_space(1))) void*)g,
        (__attribute__((address_space(3))) void*)l, 16, 0, 0);
}

// ---------------------------------------------------------------------------
// prep: fp32 weights -> bf16 (Wqkv packed [1536][512], Wp [512][512]), bias pack
// ---------------------------------------------------------------------------
__global__ __launch_bounds__(256) void prep_kernel(
    const float* __restrict__ wq, const float* __restrict__ wk,
    const float* __restrict__ wv, const float* __restrict__ wp,
    const float* __restrict__ bq, const float* __restrict__ bk,
    const float* __restrict__ bv,
    u16* __restrict__ Wqkv, u16* __restrict__ Wp, float* __restrict__ bqkv) {
    int id = blockIdx.x * 256 + threadIdx.x;   // 0 .. 1048575
    float v;
    if (id < 262144)       v = wq[id];
    else if (id < 524288)  v = wk[id - 262144];
    else if (id < 786432)  v = wv[id - 524288];
    else                   v = wp[id - 786432];
    if (id < 786432) Wqkv[id] = f2bf(v);
    else             Wp[id - 786432] = f2bf(v);
    if (id < 1536) {
        float b = (id < 512) ? bq[id] : (id < 1024 ? bk[id - 512] : bv[id - 1024]);
        bqkv[id] = b;
    }
}

// ---------------------------------------------------------------------------
// GroupNorm pass 1: per (b,g) mean & rsigma over 16 ch x 1024 spatial
// ---------------------------------------------------------------------------
__global__ __launch_bounds__(256) void gn_stats(const float* __restrict__ x,
                                                float2* __restrict__ stats) {
    int g = blockIdx.x, b = blockIdx.y;
    const float4* x4 = (const float4*)x + (size_t)(b * 512 + g * 16) * 256;
    float s = 0.f, s2 = 0.f;
    for (int i = threadIdx.x; i < 4096; i += 256) {
        float4 v = x4[i];
        s  += v.x + v.y + v.z + v.w;
        s2 += v.x * v.x + v.y * v.y + v.z * v.z + v.w * v.w;
    }
    #pragma unroll
    for (int d = 1; d < 64; d <<= 1) { s += __shfl_xor(s, d); s2 += __shfl_xor(s2, d); }
    __shared__ float red1[4], red2[4];
    int w = threadIdx.x >> 6;
    if ((threadIdx.x & 63) == 0) { red1[w] = s; red2[w] = s2; }
    __syncthreads();
    if (threadIdx.x == 0) {
        s = red1[0] + red1[1] + red1[2] + red1[3];
        s2 = red2[0] + red2[1] + red2[2] + red2[3];
        float mu = s * (1.0f / 16384.0f);
        float var = s2 * (1.0f / 16384.0f) - mu * mu;
        stats[b * 32 + g] = make_float2(mu, rsqrtf(var + 1e-5f));
    }
}

// ---------------------------------------------------------------------------
// GroupNorm pass 2 + transpose: x[b,c,s] fp32 -> h[b*1024+s][c] bf16 (token-major)
// ---------------------------------------------------------------------------
__global__ __launch_bounds__(256) void gn_apply(
    const float* __restrict__ x, const float2* __restrict__ stats,
    const float* __restrict__ gnw, const float* __restrict__ gnb,
    u16* __restrict__ h) {
    int st = blockIdx.x, b = blockIdx.y;
    int s0 = st * 64;
    __shared__ float smu[32], srs[32], sw[512], sbv[512];
    __shared__ alignas(16) u16 hs[64][520];
    int t = threadIdx.x;
    if (t < 32) { float2 v = stats[b * 32 + t]; smu[t] = v.x; srs[t] = v.y; }
    sw[t] = gnw[t]; sw[t + 256] = gnw[t + 256];
    sbv[t] = gnb[t]; sbv[t + 256] = gnb[t + 256];
    __syncthreads();
    #pragma unroll 4
    for (int it = 0; it < 32; ++it) {
        int id = it * 256 + t;
        int c = id >> 4, f4 = id & 15;
        float4 v = ((const float4*)x)[(size_t)(b * 512 + c) * 256 + (s0 >> 2) + f4];
        int g = c >> 4;
        float mu = smu[g], r = srs[g], wgt = sw[c], bia = sbv[c];
        hs[f4 * 4 + 0][c] = f2bf((v.x - mu) * r * wgt + bia);
        hs[f4 * 4 + 1][c] = f2bf((v.y - mu) * r * wgt + bia);
        hs[f4 * 4 + 2][c] = f2bf((v.z - mu) * r * wgt + bia);
        hs[f4 * 4 + 3][c] = f2bf((v.w - mu) * r * wgt + bia);
    }
    __syncthreads();
    int lane = t & 63, wrow = t >> 6;
    #pragma unroll 4
    for (int it = 0; it < 16; ++it) {
        int s = it * 4 + wrow;
        float4 vv = *(const float4*)&hs[s][lane * 8];
        *((float4*)h + (size_t)(b * 1024 + s0 + s) * 64 + lane) = vv;
    }
}

// ---------------------------------------------------------------------------
// QKV GEMM. Q: token-major, pre-scaled by 512^-0.5.
// K: per-(batch, 32-key tile) image [32 key][512 ch]; 16B blocks (64/row)
//    XOR-swizzled by (key&7) (K is LDS-staged by flash_attn).
// V: per-tile image [512 ch][32 key], UNswizzled — flash_attn consumers read
//    V fragments directly from global (L1/L2), no LDS staging.
// ---------------------------------------------------------------------------
__global__ __launch_bounds__(256, 2) void gemm_qkv(
    const u16* __restrict__ h, const u16* __restrict__ Wqkv,
    const float* __restrict__ bqkv,
    u16* __restrict__ Qo, u16* __restrict__ Ko, u16* __restrict__ Vo) {
    int n0 = blockIdx.x * 128, m0 = blockIdx.y * 128;
    __shared__ alignas(16) u16 As[128][32];
    __shared__ alignas(16) u16 Bs[128][32];
    __shared__ alignas(16) u16 Tr[128][136];
    int t = threadIdx.x, w = t >> 6, l = t & 63;
    int lane16 = l & 15, quad = l >> 4;
    int wm = w & 1, wn = w >> 1;
    v4f acc[4][4] = {};
    for (int k0 = 0; k0 < 512; k0 += 32) {
        #pragma unroll
        for (int i = 0; i < 2; ++i) {
            int id = i * 256 + t, row = id >> 2, c16 = id & 3;
            gl2lds(&h[(size_t)(m0 + row) * 512 + k0 + c16 * 8], &As[row][c16 * 8]);
            gl2lds(&Wqkv[(size_t)(n0 + row) * 512 + k0 + c16 * 8], &Bs[row][c16 * 8]);
        }
        __syncthreads();
        v8s af[4], bf[4];
        #pragma unroll
        for (int i = 0; i < 4; ++i)
            af[i] = *(const v8s*)&As[wm * 64 + i * 16 + lane16][quad * 8];
        #pragma unroll
        for (int j = 0; j < 4; ++j)
            bf[j] = *(const v8s*)&Bs[wn * 64 + j * 16 + lane16][quad * 8];
        #pragma unroll
        for (int i = 0; i < 4; ++i)
            #pragma unroll
            for (int j = 0; j < 4; ++j)
                acc[i][j] = MFMA16(af[i], bf[j], acc[i][j]);
        __syncthreads();
    }
    float bias[4];
    #pragma unroll
    for (int j = 0; j < 4; ++j) bias[j] = bqkv[n0 + wn * 64 + j * 16 + lane16];

    if (n0 < 1024) {
        // Q or K: stage [token][channel] tile in LDS
        const float qscale = (n0 < 512) ? 0.04419417382415922f : 1.0f;
        #pragma unroll
        for (int i = 0; i < 4; ++i)
            #pragma unroll
            for (int j = 0; j < 4; ++j)
                #pragma unroll
                for (int r = 0; r < 4; ++r) {
                    int row = wm * 64 + i * 16 + quad * 4 + r;
                    int col = wn * 64 + j * 16 + lane16;
                    Tr[row][col] = f2bf((acc[i][j][r] + bias[j]) * qscale);
                }
        __syncthreads();
        if (n0 < 512) {
            #pragma unroll
            for (int it = 0; it < 8; ++it) {
                int id = it * 256 + t, row = id >> 4, ch = id & 15;
                *(float4*)&Qo[(size_t)(m0 + row) * 512 + n0 + ch * 8] =
                    *(const float4*)&Tr[row][ch * 8];
            }
        } else {
            int c0 = n0 - 512, b = m0 >> 10, sb = m0 & 1023;
            #pragma unroll
            for (int it = 0; it < 8; ++it) {
                int id = it * 256 + t, row = id >> 4, ch = id & 15;
                int s = sb + row, kt = s >> 5, key = s & 31;
                int kb = ((c0 + ch * 8) >> 3) ^ (key & 7);   // XOR swizzle (64 blocks/row)
                *(float4*)&Ko[((size_t)(b * 32 + kt)) * 16384 + key * 512 + kb * 8] =
                    *(const float4*)&Tr[row][ch * 8];
            }
        }
    } else {
        // V: stage TRANSPOSED [channel][token] in LDS
        #pragma unroll
        for (int i = 0; i < 4; ++i)
            #pragma unroll
            for (int j = 0; j < 4; ++j)
                #pragma unroll
                for (int r = 0; r < 4; ++r) {
                    int row = wm * 64 + i * 16 + quad * 4 + r;
                    int col = wn * 64 + j * 16 + lane16;
                    Tr[col][row] = f2bf(acc[i][j][r] + bias[j]);
                }
        __syncthreads();
        int c0 = n0 - 1024, b = m0 >> 10, sb = m0 & 1023;
        #pragma unroll
        for (int it = 0; it < 8; ++it) {
            int id = it * 256 + t, c = id >> 4, ch8 = id & 15;
            int key0 = sb + ch8 * 8;                  // 8 consecutive keys
            int kt = key0 >> 5;
            int kblk = (key0 >> 3) & 3;               // block within 4-block row
            int ch = c0 + c;
            *(float4*)&Vo[((size_t)(b * 32 + kt)) * 16384 + (size_t)ch * 32 + kblk * 8] =
                *(const float4*)&Tr[c][ch8 * 8];
        }
    }
}

// ---------------------------------------------------------------------------
// Flash attention v4: producer/consumer wave specialization, V via L1/L2.
// Block = 64 queries, 512 thr / 8 waves, full 1024 keys in 32-key tiles.
//  Waves 0-3 (producers, (qs,kh)): QK for 32q x 16 keys via 16x16x32, Q held
//    as TWO A-frag sets (128 VGPR) -> each K B-read feeds 2 MFMAs. exp() ->
//    P image (double-buffered) + per-row l partials.
//  Waves 4-7 (consumers, (qs2,chh)): PV via 32x32x16: O^T[256ch x 32q],
//    A=V^T loaded DIRECTLY FROM GLOBAL (per-tile [512][32] image, L1/L2-hot:
//    each batch pinned to one XCD), B=P^T read once and reused over 8 ch-blocks.
//    chb-outer/key-half-inner order consumes both 16B halves of each V cache
//    line back-to-back.
// Only K is LDS-staged (double-buffered): LDS pipe traffic per tile drops
// from ~200KB to ~110KB, vmcnt drain at each barrier is 4 loads/wave, and
// LDS shrinks 139.8KB -> 74.2KB. One barrier per tile. s_setprio(1) wraps
// the MFMA clusters (producer/consumer role diversity = T5 regime).
// ---------------------------------------------------------------------------
__global__ __launch_bounds__(512, 2) void flash_attn(
    const u16* __restrict__ Q, const u16* __restrict__ Kt,
    const u16* __restrict__ Vt, u16* __restrict__ O) {
    int idx = blockIdx.x;
    int xcd = idx & 7, j = idx >> 3;          // XCD-aware: 4 batches per XCD
    int bz = xcd * 4 + (j >> 4);
    int qb = j & 15;                          // 64-query block

    __shared__ alignas(16) char lds[74240];
    u16*   KsB  = (u16*)lds;                  // [2][32][512]  64 KB
    u16*   Pb   = (u16*)(lds + 65536);        // [2][64][32]    8 KB
    float* lsum = (float*)(lds + 73728);      // [2][64]      0.5 KB

    int t = threadIdx.x, w = t >> 6, l = t & 63;
    int lane16 = l & 15, quad = l >> 4;
    int s5 = l >> 5, l31 = l & 31;

    const u16* Kb = Kt + (size_t)bz * 32 * 16384;
    const u16* Vb = Vt + (size_t)bz * 32 * 16384;

    // prologue: stage K tile 0 (each wave copies 4 KB of the 32 KB tile)
    #pragma unroll
    for (int c = 0; c < 4; ++c) {
        int ch = w * 4 + c;
        gl2lds(&Kb[ch * 512 + l * 8], &KsB[ch * 512 + l * 8]);
    }
    __syncthreads();

    if (w < 4) {
        // ================= PRODUCER =================
        int qs = w & 1, kh = w >> 1;
        int qrow = bz * 1024 + qb * 64 + qs * 32 + lane16;
        v8s qf0[16], qf1[16];
        #pragma unroll
        for (int kk = 0; kk < 16; ++kk) {
            qf0[kk] = *(const v8s*)&Q[(size_t)qrow * 512 + kk * 32 + quad * 8];
            qf1[kk] = *(const v8s*)&Q[(size_t)(qrow + 16) * 512 + kk * 32 + quad * 8];
        }
        v4f li0 = {}, li1 = {};
        int key = kh * 16 + lane16;
        int krowoff = key * 512;
        int kswz = lane16 & 7;

        for (int kt = 0; kt <= 32; ++kt) {
            if (kt + 1 < 32) {
                u16* kd = KsB + ((kt + 1) & 1) * 16384;
                const u16* ks = Kb + (size_t)(kt + 1) * 16384;
                #pragma unroll
                for (int c = 0; c < 4; ++c) {
                    int ch = w * 4 + c;
                    gl2lds(&ks[ch * 512 + l * 8], &kd[ch * 512 + l * 8]);
                }
            }
            if (kt < 32) {
                const u16* KsT = KsB + (kt & 1) * 16384;
                u16* Pt = Pb + (kt & 1) * 2048;
                v4f sA = {}, sB = {};
                __builtin_amdgcn_s_setprio(1);
                #pragma unroll
                for (int kk = 0; kk < 16; ++kk) {
                    v8s b = *(const v8s*)&KsT[krowoff + (((kk * 4 + quad) ^ kswz) * 8)];
                    sA = MFMA16(qf0[kk], b, sA);
                    sB = MFMA16(qf1[kk], b, sB);
                }
                __builtin_amdgcn_s_setprio(0);
                #pragma unroll
                for (int r = 0; r < 4; ++r) {
                    float p0 = __expf(sA[r]), p1 = __expf(sB[r]);
                    li0[r] += p0; li1[r] += p1;
                    int q0 = qs * 32 + quad * 4 + r, q1 = q0 + 16;
                    Pt[q0 * 32 + (((key >> 3) ^ ((q0 >> 1) & 3)) * 8) + (key & 7)] = f2bf(p0);
                    Pt[q1 * 32 + (((key >> 3) ^ ((q1 >> 1) & 3)) * 8) + (key & 7)] = f2bf(p1);
                }
            }
            __syncthreads();
        }
        // reduce l over the 16 keys of this wave, publish per-kh partials
        #pragma unroll
        for (int r = 0; r < 4; ++r) {
            float a = li0[r], b = li1[r];
            a += __shfl_xor(a, 1); a += __shfl_xor(a, 2);
            a += __shfl_xor(a, 4); a += __shfl_xor(a, 8);
            b += __shfl_xor(b, 1); b += __shfl_xor(b, 2);
            b += __shfl_xor(b, 4); b += __shfl_xor(b, 8);
            if (lane16 == 0) {
                lsum[kh * 64 + qs * 32 + quad * 4 + r] = a;
                lsum[kh * 64 + qs * 32 + 16 + quad * 4 + r] = b;
            }
        }
        __syncthreads();
    } else {
        // ================= CONSUMER =================
        int cw = w - 4, qs2 = cw & 1, chh = cw >> 1;
        v16f acc[8] = {};
        int q = qs2 * 32 + l31;
        int pswz = (q >> 1) & 3;

        for (int kt = 0; kt <= 32; ++kt) {
            if (kt + 1 < 32) {
                u16* kd = KsB + ((kt + 1) & 1) * 16384;
                const u16* ks = Kb + (size_t)(kt + 1) * 16384;
                #pragma unroll
                for (int c = 0; c < 4; ++c) {
                    int ch = w * 4 + c;
                    gl2lds(&ks[ch * 512 + l * 8], &kd[ch * 512 + l * 8]);
                }
            }
            if (kt >= 1) {
                int kp = (kt - 1) & 1;
                const u16* Pt    = Pb + kp * 2048;
                const u16* Vtile = Vb + (size_t)(kt - 1) * 16384;
                v8s pb0 = *(const v8s*)&Pt[q * 32 + ((s5 ^ pswz) * 8)];
                v8s pb1 = *(const v8s*)&Pt[q * 32 + (((2 + s5) ^ pswz) * 8)];
                __builtin_amdgcn_s_setprio(1);
                #pragma unroll
                for (int chb = 0; chb < 8; ++chb) {
                    int ch = chh * 256 + chb * 32 + l31;
                    const u16* vrow = &Vtile[(size_t)ch * 32];
                    v8s vf0 = *(const v8s*)&vrow[s5 * 8];
                    v8s vf1 = *(const v8s*)&vrow[(2 + s5) * 8];
                    acc[chb] = MFMA32(vf0, pb0, acc[chb]);
                    acc[chb] = MFMA32(vf1, pb1, acc[chb]);
                }
                __builtin_amdgcn_s_setprio(0);
            }
            __syncthreads();
        }
        __syncthreads();   // wait for lsum
        float inv = 1.0f / (lsum[q] + lsum[64 + q]);
        int token = bz * 1024 + qb * 64 + q;
        #pragma unroll
        for (int chb = 0; chb < 8; ++chb) {
            #pragma unroll
            for (int rg = 0; rg < 4; ++rg) {
                int ch0 = chh * 256 + chb * 32 + rg * 8 + s5 * 4;
                u16 o4[4];
                #pragma unroll
                for (int i = 0; i < 4; ++i) o4[i] = f2bf(acc[chb][rg * 4 + i] * inv);
                *(uint2*)&O[(size_t)token * 512 + ch0] = *(const uint2*)o4;
            }
        }
    }
}

// ---------------------------------------------------------------------------
// Proj GEMM + residual: out[b][c][token] = x + Wp @ O_b^T + bp
// ---------------------------------------------------------------------------
__global__ __launch_bounds__(256, 2) void gemm_proj(
    const u16* __restrict__ Wp, const u16* __restrict__ O,
    const float* __restrict__ x, const float* __restrict__ bp,
    float* __restrict__ out) {
    int n0 = blockIdx.x * 128, m0 = blockIdx.y * 128, b = blockIdx.z;
    __shared__ alignas(16) u16 As[128][32];
    __shared__ alignas(16) u16 Bs[128][32];
    int t = threadIdx.x, w = t >> 6, l = t & 63;
    int lane16 = l & 15, quad = l >> 4;
    int wm = w & 1, wn = w >> 1;
    v4f acc[4][4] = {};
    for (int k0 = 0; k0 < 512; k0 += 32) {
        #pragma unroll
        for (int i = 0; i < 2; ++i) {
            int id = i * 256 + t, row = id >> 2, c16 = id & 3;
            gl2lds(&Wp[(size_t)(m0 + row) * 512 + k0 + c16 * 8], &As[row][c16 * 8]);
            gl2lds(&O[(size_t)(b * 1024 + n0 + row) * 512 + k0 + c16 * 8], &Bs[row][c16 * 8]);
        }
        __syncthreads();
        v8s af[4], bf[4];
        #pragma unroll
        for (int i = 0; i < 4; ++i)
            af[i] = *(const v8s*)&As[wm * 64 + i * 16 + lane16][quad * 8];
        #pragma unroll
        for (int j = 0; j < 4; ++j)
            bf[j] = *(const v8s*)&Bs[wn * 64 + j * 16 + lane16][quad * 8];
        #pragma unroll
        for (int i = 0; i < 4; ++i)
            #pragma unroll
            for (int j = 0; j < 4; ++j)
                acc[i][j] = MFMA16(af[i], bf[j], acc[i][j]);
        __syncthreads();
    }
    #pragma unroll
    for (int i = 0; i < 4; ++i) {
        #pragma unroll
        for (int r = 0; r < 4; ++r) {
            int row = wm * 64 + i * 16 + quad * 4 + r;
            float bia = bp[m0 + row];
            #pragma unroll
            for (int j = 0; j < 4; ++j) {
                int col = wn * 64 + j * 16 + lane16;
                size_t idx = (size_t)(b * 512 + m0 + row) * 1024 + n0 + col;
                out[idx] = acc[i][j][r] + bia + x[idx];
            }
        }
    }
}

// ---------------------------------------------------------------------------
extern "C" void kernel_launch(void* const* d_in, const int* in_sizes, int n_in,
                              void* d_out, int out_size, void* d_ws, size_t ws_size,
                              hipStream_t stream) {
    (void)in_sizes; (void)n_in; (void)out_size; (void)ws_size;
    const float* x   = (const float*)d_in[0];
    const float* gnw = (const float*)d_in[1];
    const float* gnb = (const float*)d_in[2];
    const float* wq  = (const float*)d_in[3];
    const float* bq  = (const float*)d_in[4];
    const float* wk  = (const float*)d_in[5];
    const float* bk  = (const float*)d_in[6];
    const float* wv  = (const float*)d_in[7];
    const float* bv  = (const float*)d_in[8];
    const float* wp  = (const float*)d_in[9];
    const float* bp  = (const float*)d_in[10];
    float* out = (float*)d_out;

    char* ws = (char*)d_ws;
    u16*    Wqkv  = (u16*)(ws + 0);                       // 1.5 MB
    u16*    Wp    = (u16*)(ws + 1572864);                 // 0.5 MB
    float*  bqkv  = (float*)(ws + 2097152);               // 6 KB
    float2* stats = (float2*)(ws + 2105344);              // 8 KB
    u16*    h     = (u16*)(ws + 4194304ULL);              // 32 MB (reused as O)
    u16*    Qb    = (u16*)(ws + 4194304ULL + 33554432ULL);        // 32 MB
    u16*    Kb    = (u16*)(ws + 4194304ULL + 2ULL * 33554432ULL); // 32 MB tiled/swizzled
    u16*    Vb    = (u16*)(ws + 4194304ULL + 3ULL * 33554432ULL); // 32 MB tiled

    prep_kernel<<<4096, 256, 0, stream>>>(wq, wk, wv, wp, bq, bk, bv, Wqkv, Wp, bqkv);
    gn_stats<<<dim3(32, 32), 256, 0, stream>>>(x, stats);
    gn_apply<<<dim3(16, 32), 256, 0, stream>>>(x, stats, gnw, gnb, h);
    gemm_qkv<<<dim3(12, 256), 256, 0, stream>>>(h, Wqkv, bqkv, Qb, Kb, Vb);
    flash_attn<<<512, 512, 0, stream>>>(Qb, Kb, Vb, h /* -> O */);
    gemm_proj<<<dim3(8, 4, 32), 256, 0, stream>>>(Wp, h /* O */, x, bp, out);
}

// Round 2
// 354.342 us; speedup vs baseline: 1.1053x; 1.1053x over previous
//
#include <hip/hip_runtime.h>

typedef unsigned short u16;
typedef unsigned int u32;
typedef short v8s __attribute__((ext_vector_type(8)));
typedef float v4f __attribute__((ext_vector_type(4)));
typedef float v16f __attribute__((ext_vector_type(16)));

#define MFMA16(a, b, c) __builtin_amdgcn_mfma_f32_16x16x32_bf16((a), (b), (c), 0, 0, 0)
#define MFMA32(a, b, c) __builtin_amdgcn_mfma_f32_32x32x16_bf16((a), (b), (c), 0, 0, 0)

static __device__ __forceinline__ u16 f2bf(float f) {
    u32 u = __float_as_uint(f);
    u += 0x7fffu + ((u >> 16) & 1u);   // RNE
    return (u16)(u >> 16);
}

// async global->LDS, 16B per lane. LDS dest must be wave-uniform base + lane*16.
static __device__ __forceinline__ void gl2lds(const u16* g, u16* l) {
    __builtin_amdgcn_global_load_lds(
        (const __attribute__((address_space(1))) void*)g,
        (__attribute__((address_space(3))) void*)l, 16, 0, 0);
}

// ---------------------------------------------------------------------------
// prep: fp32 weights -> bf16 (Wqkv packed [1536][512], Wp [512][512]), bias pack
// ---------------------------------------------------------------------------
__global__ __launch_bounds__(256) void prep_kernel(
    const float* __restrict__ wq, const float* __restrict__ wk,
    const float* __restrict__ wv, const float* __restrict__ wp,
    const float* __restrict__ bq, const float* __restrict__ bk,
    const float* __restrict__ bv,
    u16* __restrict__ Wqkv, u16* __restrict__ Wp, float* __restrict__ bqkv) {
    int id = blockIdx.x * 256 + threadIdx.x;   // 0 .. 1048575
    float v;
    if (id < 262144)       v = wq[id];
    else if (id < 524288)  v = wk[id - 262144];
    else if (id < 786432)  v = wv[id - 524288];
    else                   v = wp[id - 786432];
    if (id < 786432) Wqkv[id] = f2bf(v);
    else             Wp[id - 786432] = f2bf(v);
    if (id < 1536) {
        float b = (id < 512) ? bq[id] : (id < 1024 ? bk[id - 512] : bv[id - 1024]);
        bqkv[id] = b;
    }
}

// ---------------------------------------------------------------------------
// GroupNorm pass 1: per (b,g) mean & rsigma over 16 ch x 1024 spatial
// ---------------------------------------------------------------------------
__global__ __launch_bounds__(256) void gn_stats(const float* __restrict__ x,
                                                float2* __restrict__ stats) {
    int g = blockIdx.x, b = blockIdx.y;
    const float4* x4 = (const float4*)x + (size_t)(b * 512 + g * 16) * 256;
    float s = 0.f, s2 = 0.f;
    for (int i = threadIdx.x; i < 4096; i += 256) {
        float4 v = x4[i];
        s  += v.x + v.y + v.z + v.w;
        s2 += v.x * v.x + v.y * v.y + v.z * v.z + v.w * v.w;
    }
    #pragma unroll
    for (int d = 1; d < 64; d <<= 1) { s += __shfl_xor(s, d); s2 += __shfl_xor(s2, d); }
    __shared__ float red1[4], red2[4];
    int w = threadIdx.x >> 6;
    if ((threadIdx.x & 63) == 0) { red1[w] = s; red2[w] = s2; }
    __syncthreads();
    if (threadIdx.x == 0) {
        s = red1[0] + red1[1] + red1[2] + red1[3];
        s2 = red2[0] + red2[1] + red2[2] + red2[3];
        float mu = s * (1.0f / 16384.0f);
        float var = s2 * (1.0f / 16384.0f) - mu * mu;
        stats[b * 32 + g] = make_float2(mu, rsqrtf(var + 1e-5f));
    }
}

// ---------------------------------------------------------------------------
// GroupNorm pass 2 + transpose: x[b,c,s] fp32 -> h[b*1024+s][c] bf16 (token-major)
// ---------------------------------------------------------------------------
__global__ __launch_bounds__(256) void gn_apply(
    const float* __restrict__ x, const float2* __restrict__ stats,
    const float* __restrict__ gnw, const float* __restrict__ gnb,
    u16* __restrict__ h) {
    int st = blockIdx.x, b = blockIdx.y;
    int s0 = st * 64;
    __shared__ float smu[32], srs[32], sw[512], sbv[512];
    __shared__ alignas(16) u16 hs[64][520];
    int t = threadIdx.x;
    if (t < 32) { float2 v = stats[b * 32 + t]; smu[t] = v.x; srs[t] = v.y; }
    sw[t] = gnw[t]; sw[t + 256] = gnw[t + 256];
    sbv[t] = gnb[t]; sbv[t + 256] = gnb[t + 256];
    __syncthreads();
    #pragma unroll 4
    for (int it = 0; it < 32; ++it) {
        int id = it * 256 + t;
        int c = id >> 4, f4 = id & 15;
        float4 v = ((const float4*)x)[(size_t)(b * 512 + c) * 256 + (s0 >> 2) + f4];
        int g = c >> 4;
        float mu = smu[g], r = srs[g], wgt = sw[c], bia = sbv[c];
        hs[f4 * 4 + 0][c] = f2bf((v.x - mu) * r * wgt + bia);
        hs[f4 * 4 + 1][c] = f2bf((v.y - mu) * r * wgt + bia);
        hs[f4 * 4 + 2][c] = f2bf((v.z - mu) * r * wgt + bia);
        hs[f4 * 4 + 3][c] = f2bf((v.w - mu) * r * wgt + bia);
    }
    __syncthreads();
    int lane = t & 63, wrow = t >> 6;
    #pragma unroll 4
    for (int it = 0; it < 16; ++it) {
        int s = it * 4 + wrow;
        float4 vv = *(const float4*)&hs[s][lane * 8];
        *((float4*)h + (size_t)(b * 1024 + s0 + s) * 64 + lane) = vv;
    }
}

// ---------------------------------------------------------------------------
// QKV GEMM. Q: token-major, pre-scaled by 512^-0.5.
// K: per-(batch, 32-key tile) image [32 key][512 ch]; 16B blocks (64/row)
//    XOR-swizzled by (key&7).
// V: per-tile image [512 ch][32 key]; 16B blocks (4/row) XOR-swizzled by
//    ((ch>>1)&3). Both images copied verbatim to LDS by flash_attn.
// ---------------------------------------------------------------------------
__global__ __launch_bounds__(256, 2) void gemm_qkv(
    const u16* __restrict__ h, const u16* __restrict__ Wqkv,
    const float* __restrict__ bqkv,
    u16* __restrict__ Qo, u16* __restrict__ Ko, u16* __restrict__ Vo) {
    int n0 = blockIdx.x * 128, m0 = blockIdx.y * 128;
    __shared__ alignas(16) u16 As[128][32];
    __shared__ alignas(16) u16 Bs[128][32];
    __shared__ alignas(16) u16 Tr[128][136];
    int t = threadIdx.x, w = t >> 6, l = t & 63;
    int lane16 = l & 15, quad = l >> 4;
    int wm = w & 1, wn = w >> 1;
    v4f acc[4][4] = {};
    for (int k0 = 0; k0 < 512; k0 += 32) {
        #pragma unroll
        for (int i = 0; i < 2; ++i) {
            int id = i * 256 + t, row = id >> 2, c16 = id & 3;
            gl2lds(&h[(size_t)(m0 + row) * 512 + k0 + c16 * 8], &As[row][c16 * 8]);
            gl2lds(&Wqkv[(size_t)(n0 + row) * 512 + k0 + c16 * 8], &Bs[row][c16 * 8]);
        }
        __syncthreads();
        v8s af[4], bf[4];
        #pragma unroll
        for (int i = 0; i < 4; ++i)
            af[i] = *(const v8s*)&As[wm * 64 + i * 16 + lane16][quad * 8];
        #pragma unroll
        for (int j = 0; j < 4; ++j)
            bf[j] = *(const v8s*)&Bs[wn * 64 + j * 16 + lane16][quad * 8];
        #pragma unroll
        for (int i = 0; i < 4; ++i)
            #pragma unroll
            for (int j = 0; j < 4; ++j)
                acc[i][j] = MFMA16(af[i], bf[j], acc[i][j]);
        __syncthreads();
    }
    float bias[4];
    #pragma unroll
    for (int j = 0; j < 4; ++j) bias[j] = bqkv[n0 + wn * 64 + j * 16 + lane16];

    if (n0 < 1024) {
        // Q or K: stage [token][channel] tile in LDS
        const float qscale = (n0 < 512) ? 0.04419417382415922f : 1.0f;
        #pragma unroll
        for (int i = 0; i < 4; ++i)
            #pragma unroll
            for (int j = 0; j < 4; ++j)
                #pragma unroll
                for (int r = 0; r < 4; ++r) {
                    int row = wm * 64 + i * 16 + quad * 4 + r;
                    int col = wn * 64 + j * 16 + lane16;
                    Tr[row][col] = f2bf((acc[i][j][r] + bias[j]) * qscale);
                }
        __syncthreads();
        if (n0 < 512) {
            #pragma unroll
            for (int it = 0; it < 8; ++it) {
                int id = it * 256 + t, row = id >> 4, ch = id & 15;
                *(float4*)&Qo[(size_t)(m0 + row) * 512 + n0 + ch * 8] =
                    *(const float4*)&Tr[row][ch * 8];
            }
        } else {
            int c0 = n0 - 512, b = m0 >> 10, sb = m0 & 1023;
            #pragma unroll
            for (int it = 0; it < 8; ++it) {
                int id = it * 256 + t, row = id >> 4, ch = id & 15;
                int s = sb + row, kt = s >> 5, key = s & 31;
                int kb = ((c0 + ch * 8) >> 3) ^ (key & 7);   // XOR swizzle (64 blocks/row)
                *(float4*)&Ko[((size_t)(b * 32 + kt)) * 16384 + key * 512 + kb * 8] =
                    *(const float4*)&Tr[row][ch * 8];
            }
        }
    } else {
        // V: stage TRANSPOSED [channel][token] in LDS
        #pragma unroll
        for (int i = 0; i < 4; ++i)
            #pragma unroll
            for (int j = 0; j < 4; ++j)
                #pragma unroll
                for (int r = 0; r < 4; ++r) {
                    int row = wm * 64 + i * 16 + quad * 4 + r;
                    int col = wn * 64 + j * 16 + lane16;
                    Tr[col][row] = f2bf(acc[i][j][r] + bias[j]);
                }
        __syncthreads();
        int c0 = n0 - 1024, b = m0 >> 10, sb = m0 & 1023;
        #pragma unroll
        for (int it = 0; it < 8; ++it) {
            int id = it * 256 + t, c = id >> 4, ch8 = id & 15;
            int key0 = sb + ch8 * 8;                  // 8 consecutive keys
            int kt = key0 >> 5;
            int kblk = (key0 >> 3) & 3;               // block within 4-block row
            int ch = c0 + c;
            int swz = (ch >> 1) & 3;
            *(float4*)&Vo[((size_t)(b * 32 + kt)) * 16384 + (size_t)ch * 32 +
                          ((kblk ^ swz) * 8)] =
                *(const float4*)&Tr[c][ch8 * 8];
        }
    }
}

// ---------------------------------------------------------------------------
// Flash attention v5: producer/consumer wave specialization (V back in LDS —
// round-1 showed direct-global V puts ~2 L2 latencies on the consumer
// critical path per tile; LDS staging IS the prefetch).
// Block = 64 queries, 512 thr / 8 waves, full 1024 keys in 32-key tiles.
//  Waves 0-3 (producers, (qs,kh)): QK for 32q x 16 keys via 16x16x32, Q held
//    as TWO A-frag sets (128 VGPR) -> each K B-read feeds 2 MFMAs. exp() ->
//    P image (double-buffered) + per-row l partials.
//  Waves 4-7 (consumers): CHANNEL-SPLIT — each wave owns a 128-channel
//    quarter and computes ALL 64 queries (acc[4 chb][2 qh], still 128 regs).
//    Each V fragment read feeds 2 MFMAs (one per query half): V ds_read
//    traffic per tile halves (64KB -> 32KB), P reads grow 8->16KB; net
//    -24KB/tile off the LDS pipe (the serial resource) and V-read bank
//    conflicts halve.
// One barrier per tile; K/V/P double-buffered; stages issued right after the
// barrier fly under the whole compute phase. s_setprio(1) wraps the MFMA
// clusters (producer/consumer role diversity = T5 regime).
// ---------------------------------------------------------------------------
__global__ __launch_bounds__(512, 2) void flash_attn(
    const u16* __restrict__ Q, const u16* __restrict__ Kt,
    const u16* __restrict__ Vt, u16* __restrict__ O) {
    int idx = blockIdx.x;
    int xcd = idx & 7, j = idx >> 3;          // XCD-aware: 4 batches per XCD
    int bz = xcd * 4 + (j >> 4);
    int qb = j & 15;                          // 64-query block

    __shared__ alignas(16) char lds[139776];
    u16*   KsB  = (u16*)lds;                  // [2][32][512]  64 KB
    u16*   VsB  = (u16*)(lds + 65536);        // [2][512][32]  64 KB
    u16*   Pb   = (u16*)(lds + 131072);       // [2][64][32]    8 KB
    float* lsum = (float*)(lds + 139264);     // [2][64]      0.5 KB

    int t = threadIdx.x, w = t >> 6, l = t & 63;
    int lane16 = l & 15, quad = l >> 4;
    int s5 = l >> 5, l31 = l & 31;

    const u16* Kb = Kt + (size_t)bz * 32 * 16384;
    const u16* Vb = Vt + (size_t)bz * 32 * 16384;

    // prologue: stage K tile 0 (each wave copies 4 KB of the 32 KB tile)
    #pragma unroll
    for (int c = 0; c < 4; ++c) {
        int ch = w * 4 + c;
        gl2lds(&Kb[ch * 512 + l * 8], &KsB[ch * 512 + l * 8]);
    }
    __syncthreads();

    if (w < 4) {
        // ================= PRODUCER =================
        int qs = w & 1, kh = w >> 1;
        int qrow = bz * 1024 + qb * 64 + qs * 32 + lane16;
        v8s qf0[16], qf1[16];
        #pragma unroll
        for (int kk = 0; kk < 16; ++kk) {
            qf0[kk] = *(const v8s*)&Q[(size_t)qrow * 512 + kk * 32 + quad * 8];
            qf1[kk] = *(const v8s*)&Q[(size_t)(qrow + 16) * 512 + kk * 32 + quad * 8];
        }
        v4f li0 = {}, li1 = {};
        int key = kh * 16 + lane16;
        int krowoff = key * 512;
        int kswz = lane16 & 7;

        for (int kt = 0; kt <= 32; ++kt) {
            if (kt + 1 < 32) {
                u16* kd = KsB + ((kt + 1) & 1) * 16384;
                const u16* ks = Kb + (size_t)(kt + 1) * 16384;
                #pragma unroll
                for (int c = 0; c < 4; ++c) {
                    int ch = w * 4 + c;
                    gl2lds(&ks[ch * 512 + l * 8], &kd[ch * 512 + l * 8]);
                }
            }
            if (kt < 32) {
                u16* vd = VsB + (kt & 1) * 16384;
                const u16* vs = Vb + (size_t)kt * 16384;
                #pragma unroll
                for (int c = 0; c < 4; ++c) {
                    int ch = w * 4 + c;
                    gl2lds(&vs[ch * 512 + l * 8], &vd[ch * 512 + l * 8]);
                }
                const u16* KsT = KsB + (kt & 1) * 16384;
                u16* Pt = Pb + (kt & 1) * 2048;
                v4f sA = {}, sB = {};
                __builtin_amdgcn_s_setprio(1);
                #pragma unroll
                for (int kk = 0; kk < 16; ++kk) {
                    v8s b = *(const v8s*)&KsT[krowoff + (((kk * 4 + quad) ^ kswz) * 8)];
                    sA = MFMA16(qf0[kk], b, sA);
                    sB = MFMA16(qf1[kk], b, sB);
                }
                __builtin_amdgcn_s_setprio(0);
                #pragma unroll
                for (int r = 0; r < 4; ++r) {
                    float p0 = __expf(sA[r]), p1 = __expf(sB[r]);
                    li0[r] += p0; li1[r] += p1;
                    int q0 = qs * 32 + quad * 4 + r, q1 = q0 + 16;
                    Pt[q0 * 32 + (((key >> 3) ^ ((q0 >> 1) & 3)) * 8) + (key & 7)] = f2bf(p0);
                    Pt[q1 * 32 + (((key >> 3) ^ ((q1 >> 1) & 3)) * 8) + (key & 7)] = f2bf(p1);
                }
            }
            __syncthreads();
        }
        // reduce l over the 16 keys of this wave, publish per-kh partials
        #pragma unroll
        for (int r = 0; r < 4; ++r) {
            float a = li0[r], b = li1[r];
            a += __shfl_xor(a, 1); a += __shfl_xor(a, 2);
            a += __shfl_xor(a, 4); a += __shfl_xor(a, 8);
            b += __shfl_xor(b, 1); b += __shfl_xor(b, 2);
            b += __shfl_xor(b, 4); b += __shfl_xor(b, 8);
            if (lane16 == 0) {
                lsum[kh * 64 + qs * 32 + quad * 4 + r] = a;
                lsum[kh * 64 + qs * 32 + 16 + quad * 4 + r] = b;
            }
        }
        __syncthreads();
    } else {
        // ================= CONSUMER (channel-split) =================
        int chq = w - 4;                       // 128-channel quarter
        v16f acc[4][2] = {};                   // [chb][qh]
        int q0 = l31, q1 = 32 + l31;
        int psw0 = (q0 >> 1) & 3, psw1 = (q1 >> 1) & 3;

        for (int kt = 0; kt <= 32; ++kt) {
            if (kt + 1 < 32) {
                u16* kd = KsB + ((kt + 1) & 1) * 16384;
                const u16* ks = Kb + (size_t)(kt + 1) * 16384;
                #pragma unroll
                for (int c = 0; c < 4; ++c) {
                    int ch = w * 4 + c;
                    gl2lds(&ks[ch * 512 + l * 8], &kd[ch * 512 + l * 8]);
                }
            }
            if (kt < 32) {
                u16* vd = VsB + (kt & 1) * 16384;
                const u16* vs = Vb + (size_t)kt * 16384;
                #pragma unroll
                for (int c = 0; c < 4; ++c) {
                    int ch = w * 4 + c;
                    gl2lds(&vs[ch * 512 + l * 8], &vd[ch * 512 + l * 8]);
                }
            }
            if (kt >= 1) {
                int kp = (kt - 1) & 1;
                const u16* Pt  = Pb + kp * 2048;
                const u16* VsT = VsB + kp * 16384;
                __builtin_amdgcn_s_setprio(1);
                #pragma unroll
                for (int kc = 0; kc < 2; ++kc) {
                    v8s pb0 = *(const v8s*)&Pt[q0 * 32 + (((kc * 2 + s5) ^ psw0) * 8)];
                    v8s pb1 = *(const v8s*)&Pt[q1 * 32 + (((kc * 2 + s5) ^ psw1) * 8)];
                    #pragma unroll
                    for (int chb = 0; chb < 4; ++chb) {
                        int ch = chq * 128 + chb * 32 + l31;
                        v8s vf = *(const v8s*)&VsT[ch * 32 +
                                                   (((kc * 2 + s5) ^ ((ch >> 1) & 3)) * 8)];
                        acc[chb][0] = MFMA32(vf, pb0, acc[chb][0]);
                        acc[chb][1] = MFMA32(vf, pb1, acc[chb][1]);
                    }
                }
                __builtin_amdgcn_s_setprio(0);
            }
            __syncthreads();
        }
        __syncthreads();   // wait for lsum
        float inv0 = 1.0f / (lsum[q0] + lsum[64 + q0]);
        float inv1 = 1.0f / (lsum[q1] + lsum[64 + q1]);
        int tok0 = bz * 1024 + qb * 64 + q0;
        int tok1 = tok0 + 32;
        #pragma unroll
        for (int chb = 0; chb < 4; ++chb) {
            #pragma unroll
            for (int rg = 0; rg < 4; ++rg) {
                int ch0 = chq * 128 + chb * 32 + rg * 8 + s5 * 4;
                u16 o4[4];
                #pragma unroll
                for (int i = 0; i < 4; ++i) o4[i] = f2bf(acc[chb][0][rg * 4 + i] * inv0);
                *(uint2*)&O[(size_t)tok0 * 512 + ch0] = *(const uint2*)o4;
                #pragma unroll
                for (int i = 0; i < 4; ++i) o4[i] = f2bf(acc[chb][1][rg * 4 + i] * inv1);
                *(uint2*)&O[(size_t)tok1 * 512 + ch0] = *(const uint2*)o4;
            }
        }
    }
}

// ---------------------------------------------------------------------------
// Proj GEMM + residual: out[b][c][token] = x + Wp @ O_b^T + bp
// ---------------------------------------------------------------------------
__global__ __launch_bounds__(256, 2) void gemm_proj(
    const u16* __restrict__ Wp, const u16* __restrict__ O,
    const float* __restrict__ x, const float* __restrict__ bp,
    float* __restrict__ out) {
    int n0 = blockIdx.x * 128, m0 = blockIdx.y * 128, b = blockIdx.z;
    __shared__ alignas(16) u16 As[128][32];
    __shared__ alignas(16) u16 Bs[128][32];
    int t = threadIdx.x, w = t >> 6, l = t & 63;
    int lane16 = l & 15, quad = l >> 4;
    int wm = w & 1, wn = w >> 1;
    v4f acc[4][4] = {};
    for (int k0 = 0; k0 < 512; k0 += 32) {
        #pragma unroll
        for (int i = 0; i < 2; ++i) {
            int id = i * 256 + t, row = id >> 2, c16 = id & 3;
            gl2lds(&Wp[(size_t)(m0 + row) * 512 + k0 + c16 * 8], &As[row][c16 * 8]);
            gl2lds(&O[(size_t)(b * 1024 + n0 + row) * 512 + k0 + c16 * 8], &Bs[row][c16 * 8]);
        }
        __syncthreads();
        v8s af[4], bf[4];
        #pragma unroll
        for (int i = 0; i < 4; ++i)
            af[i] = *(const v8s*)&As[wm * 64 + i * 16 + lane16][quad * 8];
        #pragma unroll
        for (int j = 0; j < 4; ++j)
            bf[j] = *(const v8s*)&Bs[wn * 64 + j * 16 + lane16][quad * 8];
        #pragma unroll
        for (int i = 0; i < 4; ++i)
            #pragma unroll
            for (int j = 0; j < 4; ++j)
                acc[i][j] = MFMA16(af[i], bf[j], acc[i][j]);
        __syncthreads();
    }
    #pragma unroll
    for (int i = 0; i < 4; ++i) {
        #pragma unroll
        for (int r = 0; r < 4; ++r) {
            int row = wm * 64 + i * 16 + quad * 4 + r;
            float bia = bp[m0 + row];
            #pragma unroll
            for (int j = 0; j < 4; ++j) {
                int col = wn * 64 + j * 16 + lane16;
                size_t idx = (size_t)(b * 512 + m0 + row) * 1024 + n0 + col;
                out[idx] = acc[i][j][r] + bia + x[idx];
            }
        }
    }
}

// ---------------------------------------------------------------------------
extern "C" void kernel_launch(void* const* d_in, const int* in_sizes, int n_in,
                              void* d_out, int out_size, void* d_ws, size_t ws_size,
                              hipStream_t stream) {
    (void)in_sizes; (void)n_in; (void)out_size; (void)ws_size;
    const float* x   = (const float*)d_in[0];
    const float* gnw = (const float*)d_in[1];
    const float* gnb = (const float*)d_in[2];
    const float* wq  = (const float*)d_in[3];
    const float* bq  = (const float*)d_in[4];
    const float* wk  = (const float*)d_in[5];
    const float* bk  = (const float*)d_in[6];
    const float* wv  = (const float*)d_in[7];
    const float* bv  = (const float*)d_in[8];
    const float* wp  = (const float*)d_in[9];
    const float* bp  = (const float*)d_in[10];
    float* out = (float*)d_out;

    char* ws = (char*)d_ws;
    u16*    Wqkv  = (u16*)(ws + 0);                       // 1.5 MB
    u16*    Wp    = (u16*)(ws + 1572864);                 // 0.5 MB
    float*  bqkv  = (float*)(ws + 2097152);               // 6 KB
    float2* stats = (float2*)(ws + 2105344);              // 8 KB
    u16*    h     = (u16*)(ws + 4194304ULL);              // 32 MB (reused as O)
    u16*    Qb    = (u16*)(ws + 4194304ULL + 33554432ULL);        // 32 MB
    u16*    Kb    = (u16*)(ws + 4194304ULL + 2ULL * 33554432ULL); // 32 MB tiled/swizzled
    u16*    Vb    = (u16*)(ws + 4194304ULL + 3ULL * 33554432ULL); // 32 MB tiled/swizzled

    prep_kernel<<<4096, 256, 0, stream>>>(wq, wk, wv, wp, bq, bk, bv, Wqkv, Wp, bqkv);
    gn_stats<<<dim3(32, 32), 256, 0, stream>>>(x, stats);
    gn_apply<<<dim3(16, 32), 256, 0, stream>>>(x, stats, gnw, gnb, h);
    gemm_qkv<<<dim3(12, 256), 256, 0, stream>>>(h, Wqkv, bqkv, Qb, Kb, Vb);
    flash_attn<<<512, 512, 0, stream>>>(Qb, Kb, Vb, h /* -> O */);
    gemm_proj<<<dim3(8, 4, 32), 256, 0, stream>>>(Wp, h /* O */, x, bp, out);
}

// Round 3
// 347.572 us; speedup vs baseline: 1.1268x; 1.0195x over previous
//
#include <hip/hip_runtime.h>

typedef unsigned short u16;
typedef unsigned int u32;
typedef short v8s __attribute__((ext_vector_type(8)));
typedef float v4f __attribute__((ext_vector_type(4)));
typedef float v16f __attribute__((ext_vector_type(16)));

#define MFMA16(a, b, c) __builtin_amdgcn_mfma_f32_16x16x32_bf16((a), (b), (c), 0, 0, 0)
#define MFMA32(a, b, c) __builtin_amdgcn_mfma_f32_32x32x16_bf16((a), (b), (c), 0, 0, 0)

static __device__ __forceinline__ u16 f2bf(float f) {
    u32 u = __float_as_uint(f);
    u += 0x7fffu + ((u >> 16) & 1u);   // RNE
    return (u16)(u >> 16);
}

// async global->LDS, 16B per lane. LDS dest must be wave-uniform base + lane*16.
static __device__ __forceinline__ void gl2lds(const u16* g, u16* l) {
    __builtin_amdgcn_global_load_lds(
        (const __attribute__((address_space(1))) void*)g,
        (__attribute__((address_space(3))) void*)l, 16, 0, 0);
}

// ---------------------------------------------------------------------------
// prep: fp32 weights -> bf16 (Wqkv packed [1536][512], Wp [512][512]), bias pack
// ---------------------------------------------------------------------------
__global__ __launch_bounds__(256) void prep_kernel(
    const float* __restrict__ wq, const float* __restrict__ wk,
    const float* __restrict__ wv, const float* __restrict__ wp,
    const float* __restrict__ bq, const float* __restrict__ bk,
    const float* __restrict__ bv,
    u16* __restrict__ Wqkv, u16* __restrict__ Wp, float* __restrict__ bqkv) {
    int id = blockIdx.x * 256 + threadIdx.x;   // 0 .. 1048575
    float v;
    if (id < 262144)       v = wq[id];
    else if (id < 524288)  v = wk[id - 262144];
    else if (id < 786432)  v = wv[id - 524288];
    else                   v = wp[id - 786432];
    if (id < 786432) Wqkv[id] = f2bf(v);
    else             Wp[id - 786432] = f2bf(v);
    if (id < 1536) {
        float b = (id < 512) ? bq[id] : (id < 1024 ? bk[id - 512] : bv[id - 1024]);
        bqkv[id] = b;
    }
}

// ---------------------------------------------------------------------------
// GroupNorm pass 1: per (b,g) mean & rsigma over 16 ch x 1024 spatial
// ---------------------------------------------------------------------------
__global__ __launch_bounds__(256) void gn_stats(const float* __restrict__ x,
                                                float2* __restrict__ stats) {
    int g = blockIdx.x, b = blockIdx.y;
    const float4* x4 = (const float4*)x + (size_t)(b * 512 + g * 16) * 256;
    float s = 0.f, s2 = 0.f;
    for (int i = threadIdx.x; i < 4096; i += 256) {
        float4 v = x4[i];
        s  += v.x + v.y + v.z + v.w;
        s2 += v.x * v.x + v.y * v.y + v.z * v.z + v.w * v.w;
    }
    #pragma unroll
    for (int d = 1; d < 64; d <<= 1) { s += __shfl_xor(s, d); s2 += __shfl_xor(s2, d); }
    __shared__ float red1[4], red2[4];
    int w = threadIdx.x >> 6;
    if ((threadIdx.x & 63) == 0) { red1[w] = s; red2[w] = s2; }
    __syncthreads();
    if (threadIdx.x == 0) {
        s = red1[0] + red1[1] + red1[2] + red1[3];
        s2 = red2[0] + red2[1] + red2[2] + red2[3];
        float mu = s * (1.0f / 16384.0f);
        float var = s2 * (1.0f / 16384.0f) - mu * mu;
        stats[b * 32 + g] = make_float2(mu, rsqrtf(var + 1e-5f));
    }
}

// ---------------------------------------------------------------------------
// GroupNorm pass 2 + transpose: x[b,c,s] fp32 -> h[b*1024+s][c] bf16 (token-major)
// ---------------------------------------------------------------------------
__global__ __launch_bounds__(256) void gn_apply(
    const float* __restrict__ x, const float2* __restrict__ stats,
    const float* __restrict__ gnw, const float* __restrict__ gnb,
    u16* __restrict__ h) {
    int st = blockIdx.x, b = blockIdx.y;
    int s0 = st * 64;
    __shared__ float smu[32], srs[32], sw[512], sbv[512];
    __shared__ alignas(16) u16 hs[64][520];
    int t = threadIdx.x;
    if (t < 32) { float2 v = stats[b * 32 + t]; smu[t] = v.x; srs[t] = v.y; }
    sw[t] = gnw[t]; sw[t + 256] = gnw[t + 256];
    sbv[t] = gnb[t]; sbv[t + 256] = gnb[t + 256];
    __syncthreads();
    #pragma unroll 4
    for (int it = 0; it < 32; ++it) {
        int id = it * 256 + t;
        int c = id >> 4, f4 = id & 15;
        float4 v = ((const float4*)x)[(size_t)(b * 512 + c) * 256 + (s0 >> 2) + f4];
        int g = c >> 4;
        float mu = smu[g], r = srs[g], wgt = sw[c], bia = sbv[c];
        hs[f4 * 4 + 0][c] = f2bf((v.x - mu) * r * wgt + bia);
        hs[f4 * 4 + 1][c] = f2bf((v.y - mu) * r * wgt + bia);
        hs[f4 * 4 + 2][c] = f2bf((v.z - mu) * r * wgt + bia);
        hs[f4 * 4 + 3][c] = f2bf((v.w - mu) * r * wgt + bia);
    }
    __syncthreads();
    int lane = t & 63, wrow = t >> 6;
    #pragma unroll 4
    for (int it = 0; it < 16; ++it) {
        int s = it * 4 + wrow;
        float4 vv = *(const float4*)&hs[s][lane * 8];
        *((float4*)h + (size_t)(b * 1024 + s0 + s) * 64 + lane) = vv;
    }
}

// ---------------------------------------------------------------------------
// QKV GEMM. Q: token-major, pre-scaled by 512^-0.5.
// K: per-(batch, 32-key tile) image [32 key][512 ch]; 16B blocks (64/row)
//    XOR-swizzled by (key&7) (K is LDS-staged by flash_attn).
// V: per-tile image [512 ch][32 key], UNswizzled — flash_attn consumers
//    register-prefetch V fragments directly from global (L1/L2).
// ---------------------------------------------------------------------------
__global__ __launch_bounds__(256, 2) void gemm_qkv(
    const u16* __restrict__ h, const u16* __restrict__ Wqkv,
    const float* __restrict__ bqkv,
    u16* __restrict__ Qo, u16* __restrict__ Ko, u16* __restrict__ Vo) {
    int n0 = blockIdx.x * 128, m0 = blockIdx.y * 128;
    __shared__ alignas(16) u16 As[128][32];
    __shared__ alignas(16) u16 Bs[128][32];
    __shared__ alignas(16) u16 Tr[128][136];
    int t = threadIdx.x, w = t >> 6, l = t & 63;
    int lane16 = l & 15, quad = l >> 4;
    int wm = w & 1, wn = w >> 1;
    v4f acc[4][4] = {};
    for (int k0 = 0; k0 < 512; k0 += 32) {
        #pragma unroll
        for (int i = 0; i < 2; ++i) {
            int id = i * 256 + t, row = id >> 2, c16 = id & 3;
            gl2lds(&h[(size_t)(m0 + row) * 512 + k0 + c16 * 8], &As[row][c16 * 8]);
            gl2lds(&Wqkv[(size_t)(n0 + row) * 512 + k0 + c16 * 8], &Bs[row][c16 * 8]);
        }
        __syncthreads();
        v8s af[4], bf[4];
        #pragma unroll
        for (int i = 0; i < 4; ++i)
            af[i] = *(const v8s*)&As[wm * 64 + i * 16 + lane16][quad * 8];
        #pragma unroll
        for (int j = 0; j < 4; ++j)
            bf[j] = *(const v8s*)&Bs[wn * 64 + j * 16 + lane16][quad * 8];
        #pragma unroll
        for (int i = 0; i < 4; ++i)
            #pragma unroll
            for (int j = 0; j < 4; ++j)
                acc[i][j] = MFMA16(af[i], bf[j], acc[i][j]);
        __syncthreads();
    }
    float bias[4];
    #pragma unroll
    for (int j = 0; j < 4; ++j) bias[j] = bqkv[n0 + wn * 64 + j * 16 + lane16];

    if (n0 < 1024) {
        // Q or K: stage [token][channel] tile in LDS
        const float qscale = (n0 < 512) ? 0.04419417382415922f : 1.0f;
        #pragma unroll
        for (int i = 0; i < 4; ++i)
            #pragma unroll
            for (int j = 0; j < 4; ++j)
                #pragma unroll
                for (int r = 0; r < 4; ++r) {
                    int row = wm * 64 + i * 16 + quad * 4 + r;
                    int col = wn * 64 + j * 16 + lane16;
                    Tr[row][col] = f2bf((acc[i][j][r] + bias[j]) * qscale);
                }
        __syncthreads();
        if (n0 < 512) {
            #pragma unroll
            for (int it = 0; it < 8; ++it) {
                int id = it * 256 + t, row = id >> 4, ch = id & 15;
                *(float4*)&Qo[(size_t)(m0 + row) * 512 + n0 + ch * 8] =
                    *(const float4*)&Tr[row][ch * 8];
            }
        } else {
            int c0 = n0 - 512, b = m0 >> 10, sb = m0 & 1023;
            #pragma unroll
            for (int it = 0; it < 8; ++it) {
                int id = it * 256 + t, row = id >> 4, ch = id & 15;
                int s = sb + row, kt = s >> 5, key = s & 31;
                int kb = ((c0 + ch * 8) >> 3) ^ (key & 7);   // XOR swizzle (64 blocks/row)
                *(float4*)&Ko[((size_t)(b * 32 + kt)) * 16384 + key * 512 + kb * 8] =
                    *(const float4*)&Tr[row][ch * 8];
            }
        }
    } else {
        // V: stage TRANSPOSED [channel][token] in LDS
        #pragma unroll
        for (int i = 0; i < 4; ++i)
            #pragma unroll
            for (int j = 0; j < 4; ++j)
                #pragma unroll
                for (int r = 0; r < 4; ++r) {
                    int row = wm * 64 + i * 16 + quad * 4 + r;
                    int col = wn * 64 + j * 16 + lane16;
                    Tr[col][row] = f2bf(acc[i][j][r] + bias[j]);
                }
        __syncthreads();
        int c0 = n0 - 1024, b = m0 >> 10, sb = m0 & 1023;
        #pragma unroll
        for (int it = 0; it < 8; ++it) {
            int id = it * 256 + t, c = id >> 4, ch8 = id & 15;
            int key0 = sb + ch8 * 8;                  // 8 consecutive keys
            int kt = key0 >> 5;
            int kblk = (key0 >> 3) & 3;               // block within 4-block row
            int ch = c0 + c;
            *(float4*)&Vo[((size_t)(b * 32 + kt)) * 16384 + (size_t)ch * 32 + kblk * 8] =
                *(const float4*)&Tr[c][ch8 * 8];
        }
    }
}

// ---------------------------------------------------------------------------
// Flash attention v6: producer/consumer wave specialization.
// Block = 64 queries, 512 thr / 8 waves, full 1024 keys in 32-key tiles.
//  Waves 0-3 (producers, (qs,kh)): QK for 32q x 16 keys via 16x16x32, Q held
//    as TWO A-frag sets (128 VGPR) -> each K B-read feeds 2 MFMAs. exp() ->
//    P image (double-buffered) + per-row l partials.
//  Waves 4-7 (consumers): channel-split, each wave owns a 128-ch quarter x
//    all 64 queries (acc[4 chb][2 qh] = 128 regs). V is NOT LDS-staged:
//    each tile's 8 V fragments are REGISTER-PREFETCHED from global (plain
//    global_load_dwordx4, one base + const offsets) one tile ahead,
//    double-buffered va/vb via an unroll-by-2 pair loop (static indexing).
//    The loads get the whole PV phase to land; the compiler's vmcnt(0)
//    drain at the tile barrier closes them harmlessly. (Round-1 failure was
//    SYNCHRONOUS global V in the MFMA loop — this is the T14 fix.)
// LDS per tile: K stage-write 32KB + K reads 64KB + P ~20KB (~116KB, was
// ~180KB); V bank conflicts eliminated; LDS 139.8KB -> 74.2KB.
// One barrier per tile. No setprio (lockstep barrier regime — it regressed).
// ---------------------------------------------------------------------------
__global__ __launch_bounds__(512, 2) void flash_attn(
    const u16* __restrict__ Q, const u16* __restrict__ Kt,
    const u16* __restrict__ Vt, u16* __restrict__ O) {
    int idx = blockIdx.x;
    int xcd = idx & 7, j = idx >> 3;          // XCD-aware: 4 batches per XCD
    int bz = xcd * 4 + (j >> 4);
    int qb = j & 15;                          // 64-query block

    __shared__ alignas(16) char lds[74240];
    u16*   KsB  = (u16*)lds;                  // [2][32][512]  64 KB
    u16*   Pb   = (u16*)(lds + 65536);        // [2][64][32]    8 KB
    float* lsum = (float*)(lds + 73728);      // [2][64]      0.5 KB

    int t = threadIdx.x, w = t >> 6, l = t & 63;
    int lane16 = l & 15, quad = l >> 4;
    int s5 = l >> 5, l31 = l & 31;

    const u16* Kb = Kt + (size_t)bz * 32 * 16384;
    const u16* Vb = Vt + (size_t)bz * 32 * 16384;

    // prologue: stage K tile 0 (each wave copies 4 KB of the 32 KB tile)
    #pragma unroll
    for (int c = 0; c < 4; ++c) {
        int ch = w * 4 + c;
        gl2lds(&Kb[ch * 512 + l * 8], &KsB[ch * 512 + l * 8]);
    }
    __syncthreads();

    if (w < 4) {
        // ================= PRODUCER =================
        int qs = w & 1, kh = w >> 1;
        int qrow = bz * 1024 + qb * 64 + qs * 32 + lane16;
        v8s qf0[16], qf1[16];
        #pragma unroll
        for (int kk = 0; kk < 16; ++kk) {
            qf0[kk] = *(const v8s*)&Q[(size_t)qrow * 512 + kk * 32 + quad * 8];
            qf1[kk] = *(const v8s*)&Q[(size_t)(qrow + 16) * 512 + kk * 32 + quad * 8];
        }
        v4f li0 = {}, li1 = {};
        int key = kh * 16 + lane16;
        int krowoff = key * 512;
        int kswz = lane16 & 7;

        for (int kt = 0; kt <= 32; ++kt) {
            if (kt + 1 < 32) {
                u16* kd = KsB + ((kt + 1) & 1) * 16384;
                const u16* ks = Kb + (size_t)(kt + 1) * 16384;
                #pragma unroll
                for (int c = 0; c < 4; ++c) {
                    int ch = w * 4 + c;
                    gl2lds(&ks[ch * 512 + l * 8], &kd[ch * 512 + l * 8]);
                }
            }
            if (kt < 32) {
                const u16* KsT = KsB + (kt & 1) * 16384;
                u16* Pt = Pb + (kt & 1) * 2048;
                v4f sA = {}, sB = {};
                #pragma unroll
                for (int kk = 0; kk < 16; ++kk) {
                    v8s b = *(const v8s*)&KsT[krowoff + (((kk * 4 + quad) ^ kswz) * 8)];
                    sA = MFMA16(qf0[kk], b, sA);
                    sB = MFMA16(qf1[kk], b, sB);
                }
                #pragma unroll
                for (int r = 0; r < 4; ++r) {
                    float p0 = __expf(sA[r]), p1 = __expf(sB[r]);
                    li0[r] += p0; li1[r] += p1;
                    int q0 = qs * 32 + quad * 4 + r, q1 = q0 + 16;
                    Pt[q0 * 32 + (((key >> 3) ^ ((q0 >> 1) & 3)) * 8) + (key & 7)] = f2bf(p0);
                    Pt[q1 * 32 + (((key >> 3) ^ ((q1 >> 1) & 3)) * 8) + (key & 7)] = f2bf(p1);
                }
            }
            __syncthreads();
        }
        // reduce l over the 16 keys of this wave, publish per-kh partials
        #pragma unroll
        for (int r = 0; r < 4; ++r) {
            float a = li0[r], b = li1[r];
            a += __shfl_xor(a, 1); a += __shfl_xor(a, 2);
            a += __shfl_xor(a, 4); a += __shfl_xor(a, 8);
            b += __shfl_xor(b, 1); b += __shfl_xor(b, 2);
            b += __shfl_xor(b, 4); b += __shfl_xor(b, 8);
            if (lane16 == 0) {
                lsum[kh * 64 + qs * 32 + quad * 4 + r] = a;
                lsum[kh * 64 + qs * 32 + 16 + quad * 4 + r] = b;
            }
        }
        __syncthreads();
    } else {
        // ================= CONSUMER (channel-split, reg-prefetched V) =====
        int chq = w - 4;                       // 128-channel quarter
        v16f acc[4][2] = {};                   // [chb][qh]
        int q0l = l31, q1l = 32 + l31;
        int psw0 = (q0l >> 1) & 3, psw1 = (q1l >> 1) & 3;
        // per-lane V base: element (chq*128 + l31)*32 + s5*8; frag offsets:
        // +chb*1024 (32 ch), +kc*16 (16 keys), +kt*16384 (tile)
        const u16* vchbase = Vb + (size_t)(chq * 128 + l31) * 32 + s5 * 8;
        v8s va[8], vb[8];

        // --- kt = 0: stage K1, prefetch V0 -> va ---
        {
            u16* kd = KsB + 16384;
            const u16* ks = Kb + 16384;
            #pragma unroll
            for (int c = 0; c < 4; ++c) {
                int ch = w * 4 + c;
                gl2lds(&ks[ch * 512 + l * 8], &kd[ch * 512 + l * 8]);
            }
            #pragma unroll
            for (int kc = 0; kc < 2; ++kc)
                #pragma unroll
                for (int chb = 0; chb < 4; ++chb)
                    va[kc * 4 + chb] = *(const v8s*)(vchbase + chb * 1024 + kc * 16);
            __syncthreads();
        }

        #pragma unroll 1
        for (int p = 0; p < 16; ++p) {
            int ktA = 2 * p + 1;               // computes tile 2p   (P parity 0)
            int ktB = 2 * p + 2;               // computes tile 2p+1 (P parity 1)
            // ---- sub A: stage K(ktA+1), prefetch V(ktA)->vb, compute va ----
            {
                if (ktA + 1 < 32) {
                    u16* kd = KsB;             // (ktA+1) even -> buffer 0
                    const u16* ks = Kb + (size_t)(ktA + 1) * 16384;
                    #pragma unroll
                    for (int c = 0; c < 4; ++c) {
                        int ch = w * 4 + c;
                        gl2lds(&ks[ch * 512 + l * 8], &kd[ch * 512 + l * 8]);
                    }
                }
                const u16* vsrc = vchbase + (size_t)ktA * 16384;
                #pragma unroll
                for (int kc = 0; kc < 2; ++kc)
                    #pragma unroll
                    for (int chb = 0; chb < 4; ++chb)
                        vb[kc * 4 + chb] = *(const v8s*)(vsrc + chb * 1024 + kc * 16);
                const u16* Pt = Pb;            // parity 0
                #pragma unroll
                for (int kc = 0; kc < 2; ++kc) {
                    v8s pb0 = *(const v8s*)&Pt[q0l * 32 + (((kc * 2 + s5) ^ psw0) * 8)];
                    v8s pb1 = *(const v8s*)&Pt[q1l * 32 + (((kc * 2 + s5) ^ psw1) * 8)];
                    #pragma unroll
                    for (int chb = 0; chb < 4; ++chb) {
                        acc[chb][0] = MFMA32(va[kc * 4 + chb], pb0, acc[chb][0]);
                        acc[chb][1] = MFMA32(va[kc * 4 + chb], pb1, acc[chb][1]);
                    }
                }
                __syncthreads();
            }
            // ---- sub B: stage K(ktB+1), prefetch V(ktB)->va, compute vb ----
            {
                if (ktB + 1 < 32) {
                    u16* kd = KsB + 16384;     // (ktB+1) odd -> buffer 1
                    const u16* ks = Kb + (size_t)(ktB + 1) * 16384;
                    #pragma unroll
                    for (int c = 0; c < 4; ++c) {
                        int ch = w * 4 + c;
                        gl2lds(&ks[ch * 512 + l * 8], &kd[ch * 512 + l * 8]);
                    }
                }
                if (ktB < 32) {
                    const u16* vsrc = vchbase + (size_t)ktB * 16384;
                    #pragma unroll
                    for (int kc = 0; kc < 2; ++kc)
                        #pragma unroll
                        for (int chb = 0; chb < 4; ++chb)
                            va[kc * 4 + chb] = *(const v8s*)(vsrc + chb * 1024 + kc * 16);
                }
                const u16* Pt = Pb + 2048;     // parity 1
                #pragma unroll
                for (int kc = 0; kc < 2; ++kc) {
                    v8s pb0 = *(const v8s*)&Pt[q0l * 32 + (((kc * 2 + s5) ^ psw0) * 8)];
                    v8s pb1 = *(const v8s*)&Pt[q1l * 32 + (((kc * 2 + s5) ^ psw1) * 8)];
                    #pragma unroll
                    for (int chb = 0; chb < 4; ++chb) {
                        acc[chb][0] = MFMA32(vb[kc * 4 + chb], pb0, acc[chb][0]);
                        acc[chb][1] = MFMA32(vb[kc * 4 + chb], pb1, acc[chb][1]);
                    }
                }
                __syncthreads();
            }
        }
        __syncthreads();   // wait for lsum
        float inv0 = 1.0f / (lsum[q0l] + lsum[64 + q0l]);
        float inv1 = 1.0f / (lsum[q1l] + lsum[64 + q1l]);
        int tok0 = bz * 1024 + qb * 64 + q0l;
        int tok1 = tok0 + 32;
        #pragma unroll
        for (int chb = 0; chb < 4; ++chb) {
            #pragma unroll
            for (int rg = 0; rg < 4; ++rg) {
                int ch0 = chq * 128 + chb * 32 + rg * 8 + s5 * 4;
                u16 o4[4];
                #pragma unroll
                for (int i = 0; i < 4; ++i) o4[i] = f2bf(acc[chb][0][rg * 4 + i] * inv0);
                *(uint2*)&O[(size_t)tok0 * 512 + ch0] = *(const uint2*)o4;
                #pragma unroll
                for (int i = 0; i < 4; ++i) o4[i] = f2bf(acc[chb][1][rg * 4 + i] * inv1);
                *(uint2*)&O[(size_t)tok1 * 512 + ch0] = *(const uint2*)o4;
            }
        }
    }
}

// ---------------------------------------------------------------------------
// Proj GEMM + residual: out[b][c][token] = x + Wp @ O_b^T + bp
// ---------------------------------------------------------------------------
__global__ __launch_bounds__(256, 2) void gemm_proj(
    const u16* __restrict__ Wp, const u16* __restrict__ O,
    const float* __restrict__ x, const float* __restrict__ bp,
    float* __restrict__ out) {
    int n0 = blockIdx.x * 128, m0 = blockIdx.y * 128, b = blockIdx.z;
    __shared__ alignas(16) u16 As[128][32];
    __shared__ alignas(16) u16 Bs[128][32];
    int t = threadIdx.x, w = t >> 6, l = t & 63;
    int lane16 = l & 15, quad = l >> 4;
    int wm = w & 1, wn = w >> 1;
    v4f acc[4][4] = {};
    for (int k0 = 0; k0 < 512; k0 += 32) {
        #pragma unroll
        for (int i = 0; i < 2; ++i) {
            int id = i * 256 + t, row = id >> 2, c16 = id & 3;
            gl2lds(&Wp[(size_t)(m0 + row) * 512 + k0 + c16 * 8], &As[row][c16 * 8]);
            gl2lds(&O[(size_t)(b * 1024 + n0 + row) * 512 + k0 + c16 * 8], &Bs[row][c16 * 8]);
        }
        __syncthreads();
        v8s af[4], bf[4];
        #pragma unroll
        for (int i = 0; i < 4; ++i)
            af[i] = *(const v8s*)&As[wm * 64 + i * 16 + lane16][quad * 8];
        #pragma unroll
        for (int j = 0; j < 4; ++j)
            bf[j] = *(const v8s*)&Bs[wn * 64 + j * 16 + lane16][quad * 8];
        #pragma unroll
        for (int i = 0; i < 4; ++i)
            #pragma unroll
            for (int j = 0; j < 4; ++j)
                acc[i][j] = MFMA16(af[i], bf[j], acc[i][j]);
        __syncthreads();
    }
    #pragma unroll
    for (int i = 0; i < 4; ++i) {
        #pragma unroll
        for (int r = 0; r < 4; ++r) {
            int row = wm * 64 + i * 16 + quad * 4 + r;
            float bia = bp[m0 + row];
            #pragma unroll
            for (int j = 0; j < 4; ++j) {
                int col = wn * 64 + j * 16 + lane16;
                size_t idx = (size_t)(b * 512 + m0 + row) * 1024 + n0 + col;
                out[idx] = acc[i][j][r] + bia + x[idx];
            }
        }
    }
}

// ---------------------------------------------------------------------------
extern "C" void kernel_launch(void* const* d_in, const int* in_sizes, int n_in,
                              void* d_out, int out_size, void* d_ws, size_t ws_size,
                              hipStream_t stream) {
    (void)in_sizes; (void)n_in; (void)out_size; (void)ws_size;
    const float* x   = (const float*)d_in[0];
    const float* gnw = (const float*)d_in[1];
    const float* gnb = (const float*)d_in[2];
    const float* wq  = (const float*)d_in[3];
    const float* bq  = (const float*)d_in[4];
    const float* wk  = (const float*)d_in[5];
    const float* bk  = (const float*)d_in[6];
    const float* wv  = (const float*)d_in[7];
    const float* bv  = (const float*)d_in[8];
    const float* wp  = (const float*)d_in[9];
    const float* bp  = (const float*)d_in[10];
    float* out = (float*)d_out;

    char* ws = (char*)d_ws;
    u16*    Wqkv  = (u16*)(ws + 0);                       // 1.5 MB
    u16*    Wp    = (u16*)(ws + 1572864);                 // 0.5 MB
    float*  bqkv  = (float*)(ws + 2097152);               // 6 KB
    float2* stats = (float2*)(ws + 2105344);              // 8 KB
    u16*    h     = (u16*)(ws + 4194304ULL);              // 32 MB (reused as O)
    u16*    Qb    = (u16*)(ws + 4194304ULL + 33554432ULL);        // 32 MB
    u16*    Kb    = (u16*)(ws + 4194304ULL + 2ULL * 33554432ULL); // 32 MB tiled/swizzled
    u16*    Vb    = (u16*)(ws + 4194304ULL + 3ULL * 33554432ULL); // 32 MB tiled

    prep_kernel<<<4096, 256, 0, stream>>>(wq, wk, wv, wp, bq, bk, bv, Wqkv, Wp, bqkv);
    gn_stats<<<dim3(32, 32), 256, 0, stream>>>(x, stats);
    gn_apply<<<dim3(16, 32), 256, 0, stream>>>(x, stats, gnw, gnb, h);
    gemm_qkv<<<dim3(12, 256), 256, 0, stream>>>(h, Wqkv, bqkv, Qb, Kb, Vb);
    flash_attn<<<512, 512, 0, stream>>>(Qb, Kb, Vb, h /* -> O */);
    gemm_proj<<<dim3(8, 4, 32), 256, 0, stream>>>(Wp, h /* O */, x, bp, out);
}